// Round 21
// baseline (156.762 us; speedup 1.0000x reference)
//
#include <hip/hip_runtime.h>
#include <cstdint>
#include <cstddef>
#include <cmath>

#define BB 256
#define TB 2048
#define NROWS (BB*TB)          // 524288 rows of [64]
#define R1 256                 // rows per k1 block
#define NBLK_K1 (NROWS/R1)     // 2048 blocks
#define NBLK1 4096             // partial granularity: 128-row groups (bit-compat R5..R20)

typedef float f32x4 __attribute__((ext_vector_type(4)));
typedef float f32x2 __attribute__((ext_vector_type(2)));

// ---- workspace layout (bytes) ----
#define OFF_X      0ull
#define SZ_X       ((size_t)NROWS*64*4)            // 128 MiB raw x_proj [bt][h]
#define OFF_PART   (OFF_X + SZ_X)
#define SZ_PART    ((size_t)128*NBLK1*4)           // 2 MiB partials [ch][4096]
#define OFF_STAT   (OFF_PART + SZ_PART)
#define SZ_STAT    (128*8)                         // f64 col sums / sumsq

// ============ K1: x_proj = kin @ W^T + 128-row-granular col sum/sumsq ============
// R9 kernel verbatim (best measured: 77-80 us across 7 runs).
__global__ __launch_bounds__(256, 2) void k1_gemm(const float* __restrict__ kin,
                                                  const float* __restrict__ Wsp,
                                                  float* __restrict__ xproj,
                                                  float* __restrict__ partials) {
  __shared__ float4 As[R1 * 16];   // 64 KB: [r][cc ^ ((r>>3)&7)]
  __shared__ f32x4 Wp[32 * 32];    // 16 KB: [p][q ^ ((p>>2)&7)], pair-interleaved
  const int tid = threadIdx.x;
  const int ty = tid >> 3;         // 0..31 -> rows 8*ty..+7
  const int tx = tid & 7;          // col-pairs p = 4*tx..+3 (cols 8*tx..+7)
  const size_t r0 = (size_t)blockIdx.x * R1;

  const f32x4* kin4 = (const f32x4*)(kin + r0 * 64);
  #pragma unroll
  for (int k = 0; k < 16; ++k) {
    int idx = k * 256 + tid;
    int r = idx >> 4, cc = idx & 15;
    f32x4 v = __builtin_nontemporal_load(&kin4[idx]);
    As[r * 16 + (cc ^ ((r >> 3) & 7))] = make_float4(v.x, v.y, v.z, v.w);
  }
  #pragma unroll
  for (int k = 0; k < 4; ++k) {
    int idx = k * 256 + tid;             // 0..1023
    int p = idx >> 5, q = idx & 31;
    float2 w0 = *(const float2*)(Wsp + (2 * p) * 64 + 2 * q);
    float2 w1 = *(const float2*)(Wsp + (2 * p + 1) * 64 + 2 * q);
    Wp[p * 32 + (q ^ ((p >> 2) & 7))] = (f32x4){w0.x, w1.x, w0.y, w1.y};
  }
  __syncthreads();

  f32x2 acc2[8][4];
  #pragma unroll
  for (int i = 0; i < 8; ++i)
    #pragma unroll
    for (int jp = 0; jp < 4; ++jp) acc2[i][jp] = (f32x2){0.f, 0.f};

  #pragma unroll 1
  for (int cc = 0; cc < 16; ++cc) {
    float4 av[8];
    f32x4 q0[4], q1[4];
    #pragma unroll
    for (int i = 0; i < 8; ++i)
      av[i] = As[(8 * ty + i) * 16 + (cc ^ (ty & 7))];
    #pragma unroll
    for (int jp = 0; jp < 4; ++jp) {
      const int p = 4 * tx + jp;
      q0[jp] = Wp[p * 32 + ((2 * cc)     ^ tx)];
      q1[jp] = Wp[p * 32 + ((2 * cc + 1) ^ tx)];
    }
    #pragma unroll
    for (int i = 0; i < 8; ++i) {
      #pragma unroll
      for (int jp = 0; jp < 4; ++jp) {
        acc2[i][jp] = __builtin_elementwise_fma((f32x2){av[i].x, av[i].x}, q0[jp].xy, acc2[i][jp]);
        acc2[i][jp] = __builtin_elementwise_fma((f32x2){av[i].y, av[i].y}, q0[jp].zw, acc2[i][jp]);
        acc2[i][jp] = __builtin_elementwise_fma((f32x2){av[i].z, av[i].z}, q1[jp].xy, acc2[i][jp]);
        acc2[i][jp] = __builtin_elementwise_fma((f32x2){av[i].w, av[i].w}, q1[jp].zw, acc2[i][jp]);
      }
    }
  }

  #pragma unroll
  for (int i = 0; i < 8; ++i) {
    const size_t row = r0 + 8 * ty + i;
    f32x4 lo = {acc2[i][0].x, acc2[i][0].y, acc2[i][1].x, acc2[i][1].y};
    f32x4 hi = {acc2[i][2].x, acc2[i][2].y, acc2[i][3].x, acc2[i][3].y};
    *(f32x4*)(xproj + row * 64 + 8 * tx)     = lo;
    *(f32x4*)(xproj + row * 64 + 8 * tx + 4) = hi;
  }

  __syncthreads();                 // As dead; reuse as stat scratch
  float* Sm = (float*)As;          // [64][33]
  float* Sq = Sm + 64 * 33;
  #pragma unroll
  for (int j = 0; j < 8; ++j) {
    const int col = 8 * tx + j;
    float s = 0.f, q = 0.f;
    #pragma unroll
    for (int i = 0; i < 8; ++i) {
      float v = (j & 1) ? acc2[i][j >> 1].y : acc2[i][j >> 1].x;
      s += v;
      q += v * v;
    }
    Sm[col * 33 + ty] = s;
    Sq[col * 33 + ty] = q;
  }
  __syncthreads();
  if (tid < 64) {
    float s0 = 0.f, q0 = 0.f, s1 = 0.f, q1 = 0.f;
    #pragma unroll
    for (int g = 0; g < 16; ++g)  { s0 += Sm[tid * 33 + g]; q0 += Sq[tid * 33 + g]; }
    #pragma unroll
    for (int g = 16; g < 32; ++g) { s1 += Sm[tid * 33 + g]; q1 += Sq[tid * 33 + g]; }
    const size_t p0 = 2 * (size_t)blockIdx.x;
    partials[(size_t)tid * NBLK1 + p0]            = s0;
    partials[(size_t)tid * NBLK1 + p0 + 1]        = s1;
    partials[(size_t)(64 + tid) * NBLK1 + p0]     = q0;
    partials[(size_t)(64 + tid) * NBLK1 + p0 + 1] = q1;
  }
}

// ============ K2a: deterministic f64 reduction (coalesced rows) ============
__global__ __launch_bounds__(256) void k2a_reduce(const float* __restrict__ partials,
                                                  double* __restrict__ statd) {
  __shared__ double sd[256];
  const int idx = blockIdx.x;              // 0..127
  double acc = 0.0;
  for (int k = threadIdx.x; k < NBLK1; k += 256)
    acc += (double)partials[(size_t)idx * NBLK1 + k];
  sd[threadIdx.x] = acc;
  __syncthreads();
  for (int s = 128; s > 0; s >>= 1) {
    if (threadIdx.x < s) sd[threadIdx.x] += sd[threadIdx.x + s];
    __syncthreads();
  }
  if (threadIdx.x == 0) statd[idx] = sd[0];
}

// ============ K345 v6: v5 + consumer LDS double-buffer (perf-only change) ============
// Consumer pre-issues next chunk's 16 b128 reads into the alternate register
// set at period start; the 64-step chain covers the LDS latency. nxt0 comes
// from the prefetched set (lgkmcnt(0)+sched_barrier before final step).
// Values identical to R20 -> bit-exact.
#define XSW 68
#define K45_LOAD(BUF, TBASE)                                             \
  { _Pragma("unroll") for (int k_ = 0; k_ < 16; ++k_) {                  \
      f32x4 v = *(const f32x4*)(cr + (TBASE) + 4 * k_);                  \
      BUF[4 * k_] = v.x; BUF[4 * k_ + 1] = v.y;                          \
      BUF[4 * k_ + 2] = v.z; BUF[4 * k_ + 3] = v.w; } }

#define K45_CHUNK(CUR, NXT0)                                  \
  { _Pragma("unroll") for (int i_ = 0; i_ < 64; ++i_) {       \
      bool sp = (mem2 >= th);                                 \
      cnt += sp ? 1u : 0u;                                    \
      float xn = (i_ < 63) ? CUR[(i_ + 1) & 63] : (NXT0);     \
      mem2 = sp ? xn : fmaf(mem2, 0.9f, xn);                  \
    } }

// producer ds_write of one staged row (lane = row t in chunk): linear padded
#define PROD_WRITE(BF)                                                        \
  { _Pragma("unroll") for (int h2 = 0; h2 < 64; ++h2) {                       \
      float pv;                                                               \
      switch (h2 & 3) {                                                       \
        case 0: pv = pregs[h2 >> 2].x; break;                                 \
        case 1: pv = pregs[h2 >> 2].y; break;                                 \
        case 2: pv = pregs[h2 >> 2].z; break;                                 \
        default: pv = pregs[h2 >> 2].w; break;                                \
      }                                                                       \
      xs[BF][h2][lane] = pv;                                                  \
    } }

#define PROD_ISSUE(C)                                                         \
  { const f32x4* xr_ = (const f32x4*)(xproj + ((size_t)b * TB +               \
                                      (size_t)(C) * 64 + lane) * 64);         \
    _Pragma("unroll") for (int k_ = 0; k_ < 16; ++k_) pregs[k_] = xr_[k_]; }

// consumer: load full row of chunk buffer BF into register array VV (16 b128)
#define CONS_LOADVV(VV, BF)                                                   \
  { const f32x4* xrow_ = (const f32x4*)&xs[BF][lane][0];                      \
    _Pragma("unroll") for (int i2 = 0; i2 < 16; ++i2) {                       \
      f32x4 v4_ = xrow_[i2];                                                  \
      VV[4*i2] = v4_.x; VV[4*i2+1] = v4_.y;                                   \
      VV[4*i2+2] = v4_.z; VV[4*i2+3] = v4_.w; } }

// consumer chain for one period: CUR = this chunk's regs, NXT = next chunk's
// regs (being prefetched); final step waits lgkmcnt(0) for NXT[0].
#define CONS_CHAIN(N, CUR, NXT)                                               \
  { unsigned long long keep = 0ull;                                           \
    _Pragma("unroll") for (int i_ = 0; i_ < 63; ++i_) {                       \
      bool sp = (mem >= 1.0f);                                                \
      unsigned long long mb = __ballot(sp);                                   \
      if (lane == i_) keep = mb;                                              \
      float xrn = CUR[i_ + 1];                                                \
      float xn = fmaf(xrn, sc, sh);                                           \
      mem = sp ? xn : fmaf(mem, 0.9f, xn);                                    \
    }                                                                         \
    asm volatile("s_waitcnt lgkmcnt(0)" ::: "memory");                        \
    __builtin_amdgcn_sched_barrier(0);                                        \
    {                                                                         \
      bool sp = (mem >= 1.0f);                                                \
      unsigned long long mb = __ballot(sp);                                   \
      if (lane == 63) keep = mb;                                              \
      float xrn = ((N) < 31) ? NXT[0] : 0.f;                                  \
      float xn = fmaf(xrn, sc, sh);                                           \
      mem = sp ? xn : fmaf(mem, 0.9f, xn);                                    \
    }                                                                         \
    masksL[(N) * 64 + lane] = keep; }

__global__ __launch_bounds__(256) void k345_scan(const float* __restrict__ xproj,
                                                 const double* __restrict__ statd,
                                                 const float* __restrict__ gamma,
                                                 const float* __restrict__ beta,
                                                 const float* __restrict__ Wc,
                                                 const float* __restrict__ lat,
                                                 const float* __restrict__ tda,
                                                 const float* __restrict__ Wtda,
                                                 const float* __restrict__ btda,
                                                 float* __restrict__ out) {
  __shared__ float xs[4][64][XSW];            // 68 KB chunk ring, [buf][h][t] padded
  __shared__ unsigned long long masksL[TB];   // 16 KB
  __shared__ float WcL[256];
  __shared__ float latL[16];
  __shared__ float thL[4];
  __shared__ float lbuf[4][TB + 4];           // 32.8 KB
  const int tid = threadIdx.x, b = blockIdx.x;
  const int lane = tid & 63;
  const int wv = tid >> 6;

  WcL[tid] = Wc[tid];
  if (tid < 16) latL[tid] = lat[tid];

  float sc = 0.f, sh = 0.f, mem = 0.f;
  f32x4 pregs[16];

  // ---- prologue: w1/w2 stage chunks 0/1 synchronously; w3 thresholds; w0 sc/sh
  if (wv == 1 || wv == 2) {
    const int c = wv - 1;
    PROD_ISSUE(c)
    PROD_WRITE(c)
  } else if (wv == 3) {
    if (lane < 4) {
      const int j = lane;
      double acc = (double)btda[j];
      for (int k = 0; k < 50; ++k)
        acc += (double)tda[b * 50 + k] * (double)Wtda[j * 50 + k];
      double sig = 1.0 / (1.0 + exp(-acc));
      thL[j] = (float)(1.0 + 0.5 * sig);
    }
  } else {
    const int h = lane;
    const double mean = statd[h] / (double)NROWS;
    const double ex2  = statd[64 + h] / (double)NROWS;
    const double var  = ex2 - mean * mean;
    const double scd  = (double)gamma[h] / sqrt(var + 1e-5);
    sc = (float)scd;
    sh = (float)((double)beta[h] - mean * scd);
  }
  __syncthreads();                            // chunks 0,1 + thL visible

  float vvA[64], vvB[64];
  if (wv == 3) { PROD_ISSUE(2) }
  else if (wv == 1) { PROD_ISSUE(3) }
  else if (wv == 0) {
    CONS_LOADVV(vvA, 0)                       // chunk 0 into vvA
    mem = fmaf(vvA[0], sc, sh);               // t=0 post-add state (same value)
  }

  // ---- pipelined scan: 16 double-periods; consume 2n/2n+1 with reg dbuf
  #pragma unroll 1
  for (int np = 0; np < 16; ++np) {
    const int n0 = 2 * np, n1 = 2 * np + 1;
    // even period n0
    if (n0 + 2 < 32 && wv == 1 + ((n0 + 2) % 3)) { PROD_WRITE((n0 + 2) & 3) }
    if (n0 + 4 < 32 && wv == 1 + ((n0 + 1) % 3)) { PROD_ISSUE(n0 + 4) }
    if (wv == 0) {
      CONS_LOADVV(vvB, (n0 + 1) & 3)          // prefetch chunk n0+1 (staged at n0-1)
      CONS_CHAIN(n0, vvA, vvB)
    }
    asm volatile("s_waitcnt lgkmcnt(0)" ::: "memory");
    __builtin_amdgcn_sched_barrier(0);
    __builtin_amdgcn_s_barrier();
    // odd period n1
    if (n1 + 2 < 32 && wv == 1 + ((n1 + 2) % 3)) { PROD_WRITE((n1 + 2) & 3) }
    if (n1 + 4 < 32 && wv == 1 + ((n1 + 1) % 3)) { PROD_ISSUE(n1 + 4) }
    if (wv == 0) {
      if (n1 < 31) { CONS_LOADVV(vvA, (n1 + 1) & 3) }   // prefetch chunk n1+1
      CONS_CHAIN(n1, vvB, vvA)
    }
    asm volatile("s_waitcnt lgkmcnt(0)" ::: "memory");
    __builtin_amdgcn_sched_barrier(0);
    __builtin_amdgcn_s_barrier();
  }
  __syncthreads();                            // masksL complete & visible

  // ---- phase B: cur2 for all t from LDS masks (identical math)
  #pragma unroll 1
  for (int c = 0; c < 8; ++c) {
    const int t = c * 256 + tid;
    const unsigned long long m = masksL[t];
    const unsigned lo = (unsigned)m, hi = (unsigned)(m >> 32);
    float v0 = 0.f, v1 = 0.f, v2 = 0.f, v3 = 0.f;
    #pragma unroll
    for (int hh = 0; hh < 32; ++hh) {
      const float bit = (float)((lo >> hh) & 1u);
      v0 = fmaf(bit, WcL[hh],       v0);
      v1 = fmaf(bit, WcL[64 + hh],  v1);
      v2 = fmaf(bit, WcL[128 + hh], v2);
      v3 = fmaf(bit, WcL[192 + hh], v3);
    }
    #pragma unroll
    for (int hh = 32; hh < 64; ++hh) {
      const float bit = (float)((hi >> (hh - 32)) & 1u);
      v0 = fmaf(bit, WcL[hh],       v0);
      v1 = fmaf(bit, WcL[64 + hh],  v1);
      v2 = fmaf(bit, WcL[128 + hh], v2);
      v3 = fmaf(bit, WcL[192 + hh], v3);
    }
    { float cx = v0 * latL[0];  cx = fmaf(v1, latL[4],  cx); cx = fmaf(v2, latL[8],  cx); cx = fmaf(v3, latL[12], cx); lbuf[0][t] = cx; }
    { float cx = v0 * latL[1];  cx = fmaf(v1, latL[5],  cx); cx = fmaf(v2, latL[9],  cx); cx = fmaf(v3, latL[13], cx); lbuf[1][t] = cx; }
    { float cx = v0 * latL[2];  cx = fmaf(v1, latL[6],  cx); cx = fmaf(v2, latL[10], cx); cx = fmaf(v3, latL[14], cx); lbuf[2][t] = cx; }
    { float cx = v0 * latL[3];  cx = fmaf(v1, latL[7],  cx); cx = fmaf(v2, latL[11], cx); cx = fmaf(v3, latL[15], cx); lbuf[3][t] = cx; }
  }
  __syncthreads();
  if (tid >= 64) return;

  // ---- phase C: wave 0 scans layer-2 from LDS; lanes mirror 4 chains
  const int j4 = tid & 3;
  const float th = thL[j4];
  const float* cr = lbuf[j4];
  float ca[64], cb[64];

  K45_LOAD(ca, 0)
  float mem2 = ca[0];
  unsigned cnt = 0;

  #pragma unroll 1
  for (int t0 = 0; t0 < TB; t0 += 128) {
    K45_LOAD(cb, t0 + 64)
    K45_CHUNK(ca, cb[0])
    if (t0 + 128 < TB) { K45_LOAD(ca, t0 + 128) }
    K45_CHUNK(cb, ca[0])
  }
  if (tid < 4) out[b * 4 + j4] = (float)cnt;
}

extern "C" void kernel_launch(void* const* d_in, const int* in_sizes, int n_in,
                              void* d_out, int out_size, void* d_ws, size_t ws_size,
                              hipStream_t stream) {
  const float* kin   = (const float*)d_in[0];
  const float* tda   = (const float*)d_in[1];
  const float* Wsp   = (const float*)d_in[2];
  const float* gamma = (const float*)d_in[3];
  const float* beta  = (const float*)d_in[4];
  const float* Wc    = (const float*)d_in[5];
  const float* lat   = (const float*)d_in[6];
  const float* Wtda  = (const float*)d_in[7];
  const float* btda  = (const float*)d_in[8];

  char* ws = (char*)d_ws;
  float*  xproj    = (float*)(ws + OFF_X);
  float*  partials = (float*)(ws + OFF_PART);
  double* statd    = (double*)(ws + OFF_STAT);
  float*  out      = (float*)d_out;

  k1_gemm  <<<dim3(NBLK_K1), dim3(256), 0, stream>>>(kin, Wsp, xproj, partials);
  k2a_reduce<<<dim3(128),  dim3(256), 0, stream>>>(partials, statd);
  k345_scan<<<dim3(BB),    dim3(256), 0, stream>>>(xproj, statd, gamma, beta,
                                                   Wc, lat, tda, Wtda, btda, out);
}

// Round 22
// 148.508 us; speedup vs baseline: 1.0556x; 1.0556x over previous
//
#include <hip/hip_runtime.h>
#include <cstdint>
#include <cstddef>
#include <cmath>

#define BB 256
#define TB 2048
#define NROWS (BB*TB)          // 524288 rows of [64]
#define R1 256                 // rows per k1 block
#define NBLK_K1 (NROWS/R1)     // 2048 blocks
#define NBLK1 4096             // partial granularity: 128-row groups (bit-compat R5..R21)

typedef float f32x4 __attribute__((ext_vector_type(4)));
typedef float f32x2 __attribute__((ext_vector_type(2)));

// ---- workspace layout (bytes) ----
#define OFF_X      0ull
#define SZ_X       ((size_t)NROWS*64*4)            // 128 MiB raw x_proj [bt][h]
#define OFF_PART   (OFF_X + SZ_X)
#define SZ_PART    ((size_t)128*NBLK1*4)           // 2 MiB partials [ch][4096]
#define OFF_STAT   (OFF_PART + SZ_PART)
#define SZ_STAT    (128*8)                         // f64 col sums / sumsq

// ============ K1: x_proj = kin @ W^T + 128-row-granular col sum/sumsq ============
// R9 kernel verbatim (best measured: 77-80 us across 8 runs).
__global__ __launch_bounds__(256, 2) void k1_gemm(const float* __restrict__ kin,
                                                  const float* __restrict__ Wsp,
                                                  float* __restrict__ xproj,
                                                  float* __restrict__ partials) {
  __shared__ float4 As[R1 * 16];   // 64 KB: [r][cc ^ ((r>>3)&7)]
  __shared__ f32x4 Wp[32 * 32];    // 16 KB: [p][q ^ ((p>>2)&7)], pair-interleaved
  const int tid = threadIdx.x;
  const int ty = tid >> 3;         // 0..31 -> rows 8*ty..+7
  const int tx = tid & 7;          // col-pairs p = 4*tx..+3 (cols 8*tx..+7)
  const size_t r0 = (size_t)blockIdx.x * R1;

  const f32x4* kin4 = (const f32x4*)(kin + r0 * 64);
  #pragma unroll
  for (int k = 0; k < 16; ++k) {
    int idx = k * 256 + tid;
    int r = idx >> 4, cc = idx & 15;
    f32x4 v = __builtin_nontemporal_load(&kin4[idx]);
    As[r * 16 + (cc ^ ((r >> 3) & 7))] = make_float4(v.x, v.y, v.z, v.w);
  }
  #pragma unroll
  for (int k = 0; k < 4; ++k) {
    int idx = k * 256 + tid;             // 0..1023
    int p = idx >> 5, q = idx & 31;
    float2 w0 = *(const float2*)(Wsp + (2 * p) * 64 + 2 * q);
    float2 w1 = *(const float2*)(Wsp + (2 * p + 1) * 64 + 2 * q);
    Wp[p * 32 + (q ^ ((p >> 2) & 7))] = (f32x4){w0.x, w1.x, w0.y, w1.y};
  }
  __syncthreads();

  f32x2 acc2[8][4];
  #pragma unroll
  for (int i = 0; i < 8; ++i)
    #pragma unroll
    for (int jp = 0; jp < 4; ++jp) acc2[i][jp] = (f32x2){0.f, 0.f};

  #pragma unroll 1
  for (int cc = 0; cc < 16; ++cc) {
    float4 av[8];
    f32x4 q0[4], q1[4];
    #pragma unroll
    for (int i = 0; i < 8; ++i)
      av[i] = As[(8 * ty + i) * 16 + (cc ^ (ty & 7))];
    #pragma unroll
    for (int jp = 0; jp < 4; ++jp) {
      const int p = 4 * tx + jp;
      q0[jp] = Wp[p * 32 + ((2 * cc)     ^ tx)];
      q1[jp] = Wp[p * 32 + ((2 * cc + 1) ^ tx)];
    }
    #pragma unroll
    for (int i = 0; i < 8; ++i) {
      #pragma unroll
      for (int jp = 0; jp < 4; ++jp) {
        acc2[i][jp] = __builtin_elementwise_fma((f32x2){av[i].x, av[i].x}, q0[jp].xy, acc2[i][jp]);
        acc2[i][jp] = __builtin_elementwise_fma((f32x2){av[i].y, av[i].y}, q0[jp].zw, acc2[i][jp]);
        acc2[i][jp] = __builtin_elementwise_fma((f32x2){av[i].z, av[i].z}, q1[jp].xy, acc2[i][jp]);
        acc2[i][jp] = __builtin_elementwise_fma((f32x2){av[i].w, av[i].w}, q1[jp].zw, acc2[i][jp]);
      }
    }
  }

  #pragma unroll
  for (int i = 0; i < 8; ++i) {
    const size_t row = r0 + 8 * ty + i;
    f32x4 lo = {acc2[i][0].x, acc2[i][0].y, acc2[i][1].x, acc2[i][1].y};
    f32x4 hi = {acc2[i][2].x, acc2[i][2].y, acc2[i][3].x, acc2[i][3].y};
    *(f32x4*)(xproj + row * 64 + 8 * tx)     = lo;
    *(f32x4*)(xproj + row * 64 + 8 * tx + 4) = hi;
  }

  __syncthreads();                 // As dead; reuse as stat scratch
  float* Sm = (float*)As;          // [64][33]
  float* Sq = Sm + 64 * 33;
  #pragma unroll
  for (int j = 0; j < 8; ++j) {
    const int col = 8 * tx + j;
    float s = 0.f, q = 0.f;
    #pragma unroll
    for (int i = 0; i < 8; ++i) {
      float v = (j & 1) ? acc2[i][j >> 1].y : acc2[i][j >> 1].x;
      s += v;
      q += v * v;
    }
    Sm[col * 33 + ty] = s;
    Sq[col * 33 + ty] = q;
  }
  __syncthreads();
  if (tid < 64) {
    float s0 = 0.f, q0 = 0.f, s1 = 0.f, q1 = 0.f;
    #pragma unroll
    for (int g = 0; g < 16; ++g)  { s0 += Sm[tid * 33 + g]; q0 += Sq[tid * 33 + g]; }
    #pragma unroll
    for (int g = 16; g < 32; ++g) { s1 += Sm[tid * 33 + g]; q1 += Sq[tid * 33 + g]; }
    const size_t p0 = 2 * (size_t)blockIdx.x;
    partials[(size_t)tid * NBLK1 + p0]            = s0;
    partials[(size_t)tid * NBLK1 + p0 + 1]        = s1;
    partials[(size_t)(64 + tid) * NBLK1 + p0]     = q0;
    partials[(size_t)(64 + tid) * NBLK1 + p0 + 1] = q1;
  }
}

// ============ K2a: deterministic f64 reduction (coalesced rows) ============
__global__ __launch_bounds__(256) void k2a_reduce(const float* __restrict__ partials,
                                                  double* __restrict__ statd) {
  __shared__ double sd[256];
  const int idx = blockIdx.x;              // 0..127
  double acc = 0.0;
  for (int k = threadIdx.x; k < NBLK1; k += 256)
    acc += (double)partials[(size_t)idx * NBLK1 + k];
  sd[threadIdx.x] = acc;
  __syncthreads();
  for (int s = 128; s > 0; s >>= 1) {
    if (threadIdx.x < s) sd[threadIdx.x] += sd[threadIdx.x + s];
    __syncthreads();
  }
  if (threadIdx.x == 0) statd[idx] = sd[0];
}

// ============ K345 v7: v5 + ballot-free scan (per-lane bits) + parallel transpose ============
// Phase A consumer: lane h accumulates its OWN spike bits over 64 steps (v_or
// + v_cndmask, all-VGPR, no cross-lane) into masksT[chunk][h]. New transpose
// phase (all 4 waves, no serial dep) ballots masksT bit-columns into masksL[t]
// -- same values as the old per-step ballot. Phases B/C unchanged. Bit-exact.
#define XSW 68
#define K45_LOAD(BUF, TBASE)                                             \
  { _Pragma("unroll") for (int k_ = 0; k_ < 16; ++k_) {                  \
      f32x4 v = *(const f32x4*)(cr + (TBASE) + 4 * k_);                  \
      BUF[4 * k_] = v.x; BUF[4 * k_ + 1] = v.y;                          \
      BUF[4 * k_ + 2] = v.z; BUF[4 * k_ + 3] = v.w; } }

#define K45_CHUNK(CUR, NXT0)                                  \
  { _Pragma("unroll") for (int i_ = 0; i_ < 64; ++i_) {       \
      bool sp = (mem2 >= th);                                 \
      cnt += sp ? 1u : 0u;                                    \
      float xn = (i_ < 63) ? CUR[(i_ + 1) & 63] : (NXT0);     \
      mem2 = sp ? xn : fmaf(mem2, 0.9f, xn);                  \
    } }

// producer ds_write of one staged row (lane = row t in chunk): linear padded
#define PROD_WRITE(BF)                                                        \
  { _Pragma("unroll") for (int h2 = 0; h2 < 64; ++h2) {                       \
      float pv;                                                               \
      switch (h2 & 3) {                                                       \
        case 0: pv = pregs[h2 >> 2].x; break;                                 \
        case 1: pv = pregs[h2 >> 2].y; break;                                 \
        case 2: pv = pregs[h2 >> 2].z; break;                                 \
        default: pv = pregs[h2 >> 2].w; break;                                \
      }                                                                       \
      xs[BF][h2][lane] = pv;                                                  \
    } }

#define PROD_ISSUE(C)                                                         \
  { const f32x4* xr_ = (const f32x4*)(xproj + ((size_t)b * TB +               \
                                      (size_t)(C) * 64 + lane) * 64);         \
    _Pragma("unroll") for (int k_ = 0; k_ < 16; ++k_) pregs[k_] = xr_[k_]; }

__global__ __launch_bounds__(256) void k345_scan(const float* __restrict__ xproj,
                                                 const double* __restrict__ statd,
                                                 const float* __restrict__ gamma,
                                                 const float* __restrict__ beta,
                                                 const float* __restrict__ Wc,
                                                 const float* __restrict__ lat,
                                                 const float* __restrict__ tda,
                                                 const float* __restrict__ Wtda,
                                                 const float* __restrict__ btda,
                                                 float* __restrict__ out) {
  __shared__ float xs[4][64][XSW];            // 68 KB chunk ring, [buf][h][t] padded
  __shared__ unsigned long long masksT[TB];   // 16 KB, [chunk][h] = bits over t
  __shared__ unsigned long long masksL[TB];   // 16 KB, [t] = bits over h
  __shared__ float WcL[256];
  __shared__ float latL[16];
  __shared__ float thL[4];
  __shared__ float lbuf[4][TB + 4];           // 32.8 KB
  const int tid = threadIdx.x, b = blockIdx.x;
  const int lane = tid & 63;
  const int wv = tid >> 6;

  WcL[tid] = Wc[tid];
  if (tid < 16) latL[tid] = lat[tid];

  float sc = 0.f, sh = 0.f, mem = 0.f;
  f32x4 pregs[16];

  // ---- prologue: w1/w2 stage chunks 0/1 synchronously; w3 thresholds; w0 sc/sh
  if (wv == 1 || wv == 2) {
    const int c = wv - 1;
    PROD_ISSUE(c)
    PROD_WRITE(c)
  } else if (wv == 3) {
    if (lane < 4) {
      const int j = lane;
      double acc = (double)btda[j];
      for (int k = 0; k < 50; ++k)
        acc += (double)tda[b * 50 + k] * (double)Wtda[j * 50 + k];
      double sig = 1.0 / (1.0 + exp(-acc));
      thL[j] = (float)(1.0 + 0.5 * sig);
    }
  } else {
    const int h = lane;
    const double mean = statd[h] / (double)NROWS;
    const double ex2  = statd[64 + h] / (double)NROWS;
    const double var  = ex2 - mean * mean;
    const double scd  = (double)gamma[h] / sqrt(var + 1e-5);
    sc = (float)scd;
    sh = (float)((double)beta[h] - mean * scd);
  }
  __syncthreads();                            // chunks 0,1 + thL visible

  if (wv == 3) { PROD_ISSUE(2) }
  else if (wv == 1) { PROD_ISSUE(3) }
  else if (wv == 0) {
    mem = fmaf(xs[0][lane][0], sc, sh);       // t=0 post-add state
  }

  // ---- pipelined scan: 32 periods; consume n (ballot-free), write n+2, issue n+4
  #pragma unroll 1
  for (int n = 0; n < 32; ++n) {
    if (n + 2 < 32 && wv == 1 + ((n + 2) % 3)) {
      const int bf = (n + 2) & 3;
      PROD_WRITE(bf)
    }
    if (n + 4 < 32 && wv == 1 + ((n + 1) % 3)) {
      PROD_ISSUE(n + 4)
    }
    if (wv == 0) {
      const int bf = n & 3;
      const f32x4* xrow = (const f32x4*)&xs[bf][lane][0];   // 272B base, 16-aligned
      float vv[64];
      #pragma unroll
      for (int i = 0; i < 16; ++i) {
        f32x4 v4 = xrow[i];
        vv[4*i] = v4.x; vv[4*i+1] = v4.y; vv[4*i+2] = v4.z; vv[4*i+3] = v4.w;
      }
      const float nxt0 = (n < 31) ? xs[(n + 1) & 3][lane][0] : 0.f;
      unsigned keepLo = 0u, keepHi = 0u;
      #pragma unroll
      for (int i_ = 0; i_ < 64; ++i_) {
        bool sp = (mem >= 1.0f);
        if (i_ < 32) { unsigned t2 = keepLo | (1u << i_);        keepLo = sp ? t2 : keepLo; }
        else         { unsigned t2 = keepHi | (1u << (i_ - 32)); keepHi = sp ? t2 : keepHi; }
        float xrn = (i_ < 63) ? vv[(i_ + 1) & 63] : nxt0;
        float xn = fmaf(xrn, sc, sh);
        mem = sp ? xn : fmaf(mem, 0.9f, xn);
      }
      masksT[n * 64 + lane] = ((unsigned long long)keepHi << 32) | keepLo;
    }
    asm volatile("s_waitcnt lgkmcnt(0)" ::: "memory");
    __builtin_amdgcn_sched_barrier(0);
    __builtin_amdgcn_s_barrier();
  }
  __syncthreads();                            // masksT complete & visible

  // ---- transpose: masksT[chunk][h] -> masksL[chunk*64+tb]; 4 waves x 8 chunks
  #pragma unroll 1
  for (int cc2 = 0; cc2 < 8; ++cc2) {
    const int chunk = wv * 8 + cc2;
    const unsigned long long m = masksT[chunk * 64 + lane];
    const unsigned mlo = (unsigned)m, mhi = (unsigned)(m >> 32);
    unsigned long long keep = 0ull;
    #pragma unroll
    for (int tb = 0; tb < 64; ++tb) {
      bool sp = (((tb < 32) ? (mlo >> tb) : (mhi >> (tb - 32))) & 1u) != 0u;
      unsigned long long mb = __ballot(sp);
      if (lane == tb) keep = mb;
    }
    masksL[chunk * 64 + lane] = keep;
  }
  __syncthreads();                            // masksL complete & visible

  // ---- phase B: cur2 for all t from LDS masks (identical math)
  #pragma unroll 1
  for (int c = 0; c < 8; ++c) {
    const int t = c * 256 + tid;
    const unsigned long long m = masksL[t];
    const unsigned lo = (unsigned)m, hi = (unsigned)(m >> 32);
    float v0 = 0.f, v1 = 0.f, v2 = 0.f, v3 = 0.f;
    #pragma unroll
    for (int hh = 0; hh < 32; ++hh) {
      const float bit = (float)((lo >> hh) & 1u);
      v0 = fmaf(bit, WcL[hh],       v0);
      v1 = fmaf(bit, WcL[64 + hh],  v1);
      v2 = fmaf(bit, WcL[128 + hh], v2);
      v3 = fmaf(bit, WcL[192 + hh], v3);
    }
    #pragma unroll
    for (int hh = 32; hh < 64; ++hh) {
      const float bit = (float)((hi >> (hh - 32)) & 1u);
      v0 = fmaf(bit, WcL[hh],       v0);
      v1 = fmaf(bit, WcL[64 + hh],  v1);
      v2 = fmaf(bit, WcL[128 + hh], v2);
      v3 = fmaf(bit, WcL[192 + hh], v3);
    }
    { float cx = v0 * latL[0];  cx = fmaf(v1, latL[4],  cx); cx = fmaf(v2, latL[8],  cx); cx = fmaf(v3, latL[12], cx); lbuf[0][t] = cx; }
    { float cx = v0 * latL[1];  cx = fmaf(v1, latL[5],  cx); cx = fmaf(v2, latL[9],  cx); cx = fmaf(v3, latL[13], cx); lbuf[1][t] = cx; }
    { float cx = v0 * latL[2];  cx = fmaf(v1, latL[6],  cx); cx = fmaf(v2, latL[10], cx); cx = fmaf(v3, latL[14], cx); lbuf[2][t] = cx; }
    { float cx = v0 * latL[3];  cx = fmaf(v1, latL[7],  cx); cx = fmaf(v2, latL[11], cx); cx = fmaf(v3, latL[15], cx); lbuf[3][t] = cx; }
  }
  __syncthreads();
  if (tid >= 64) return;

  // ---- phase C: wave 0 scans layer-2 from LDS; lanes mirror 4 chains
  const int j4 = tid & 3;
  const float th = thL[j4];
  const float* cr = lbuf[j4];
  float ca[64], cb[64];

  K45_LOAD(ca, 0)
  float mem2 = ca[0];
  unsigned cnt = 0;

  #pragma unroll 1
  for (int t0 = 0; t0 < TB; t0 += 128) {
    K45_LOAD(cb, t0 + 64)
    K45_CHUNK(ca, cb[0])
    if (t0 + 128 < TB) { K45_LOAD(ca, t0 + 128) }
    K45_CHUNK(cb, ca[0])
  }
  if (tid < 4) out[b * 4 + j4] = (float)cnt;
}

extern "C" void kernel_launch(void* const* d_in, const int* in_sizes, int n_in,
                              void* d_out, int out_size, void* d_ws, size_t ws_size,
                              hipStream_t stream) {
  const float* kin   = (const float*)d_in[0];
  const float* tda   = (const float*)d_in[1];
  const float* Wsp   = (const float*)d_in[2];
  const float* gamma = (const float*)d_in[3];
  const float* beta  = (const float*)d_in[4];
  const float* Wc    = (const float*)d_in[5];
  const float* lat   = (const float*)d_in[6];
  const float* Wtda  = (const float*)d_in[7];
  const float* btda  = (const float*)d_in[8];

  char* ws = (char*)d_ws;
  float*  xproj    = (float*)(ws + OFF_X);
  float*  partials = (float*)(ws + OFF_PART);
  double* statd    = (double*)(ws + OFF_STAT);
  float*  out      = (float*)d_out;

  k1_gemm  <<<dim3(NBLK_K1), dim3(256), 0, stream>>>(kin, Wsp, xproj, partials);
  k2a_reduce<<<dim3(128),  dim3(256), 0, stream>>>(partials, statd);
  k345_scan<<<dim3(BB),    dim3(256), 0, stream>>>(xproj, statd, gamma, beta,
                                                   Wc, lat, tda, Wtda, btda, out);
}